// Round 8
// baseline (264.581 us; speedup 1.0000x reference)
//
#include <hip/hip_runtime.h>
#include <stdint.h>

typedef __bf16 bf16;
typedef __bf16 bf16x4 __attribute__((ext_vector_type(4)));
typedef __bf16 bf16x8 __attribute__((ext_vector_type(8)));
typedef float f32x4 __attribute__((ext_vector_type(4)));

#define MFMA(a, b, c) __builtin_amdgcn_mfma_f32_16x16x32_bf16(a, b, c, 0, 0, 0)

// ---------------- prep kernels ----------------

__global__ void k_cast_x(const float* __restrict__ x, bf16* __restrict__ xb) {
    int i = (blockIdx.x * 256 + threadIdx.x) * 4;
    float4 v = *reinterpret_cast<const float4*>(x + i);
    bf16x4 o = { (bf16)v.x, (bf16)v.y, (bf16)v.z, (bf16)v.w };
    *reinterpret_cast<bf16x4*>(xb + i) = o;
}

__global__ void k_prep_w(const float* __restrict__ w0, const float* __restrict__ w1,
                         const float* __restrict__ w2, const float* __restrict__ w3,
                         bf16* __restrict__ o0, bf16* __restrict__ o1,
                         bf16* __restrict__ o2, bf16* __restrict__ o3) {
    __shared__ float t[64][65];
    const float* w; bf16* o;
    if (blockIdx.z == 0)      { w = w0; o = o0; }
    else if (blockIdx.z == 1) { w = w1; o = o1; }
    else if (blockIdx.z == 2) { w = w2; o = o2; }
    else                      { w = w3; o = o3; }
    int n0 = blockIdx.x * 64, k0 = blockIdx.y * 64;
    int tx = threadIdx.x & 63, ty = threadIdx.x >> 6;
    #pragma unroll
    for (int s = 0; s < 16; ++s) {
        int r = ty * 16 + s;
        t[r][tx] = w[(k0 + r) * 512 + n0 + tx];
    }
    __syncthreads();
    #pragma unroll
    for (int s = 0; s < 16; ++s) {
        int r = ty * 16 + s;
        o[(n0 + r) * 512 + k0 + tx] = (bf16)t[tx][r];
    }
}

__global__ void k_prep_er(const float* __restrict__ er, bf16* __restrict__ erB) {
    int i = blockIdx.x * 256 + threadIdx.x;
    int r = i >> 6;
    erB[i] = (r < 2048) ? (bf16)er[i] : (bf16)0.0f;
}

// ---------------- 64x64 GEMM tile core, BK=128 (8 barriers instead of 32) ----------------

__device__ __forceinline__ void gemm_tile_64x64_bk128(
    const bf16* __restrict__ A, const bf16* __restrict__ BT,
    int m0, int n0, bf16* la, bf16* lb, f32x4 (&acc)[4])
{
    const int tid = threadIdx.x;
    const int w = tid >> 6, lane = tid & 63;
    const int fm = lane & 15, fg = lane >> 4;

    // staging map: 4 chunks per thread per matrix; row = cid>>4, logical chunk g = cid&15
    bf16x8 pa[4], pb[4];
    #pragma unroll
    for (int t = 0; t < 4; ++t) {
        const int cid = t * 256 + tid;
        const int row = cid >> 4, g = cid & 15;
        pa[t] = *reinterpret_cast<const bf16x8*>(&A [(m0 + row) * 512 + g * 8]);
        pb[t] = *reinterpret_cast<const bf16x8*>(&BT[(n0 + row) * 512 + g * 8]);
    }
    for (int kt = 0; kt < 4; ++kt) {
        __syncthreads();
        #pragma unroll
        for (int t = 0; t < 4; ++t) {
            const int cid = t * 256 + tid;
            const int row = cid >> 4, g = cid & 15;
            const int ph = g ^ (row & 15);
            *reinterpret_cast<bf16x8*>(&la[row * 128 + ph * 8]) = pa[t];
            *reinterpret_cast<bf16x8*>(&lb[row * 128 + ph * 8]) = pb[t];
        }
        __syncthreads();
        if (kt < 3) {
            const int kb = (kt + 1) * 128;
            #pragma unroll
            for (int t = 0; t < 4; ++t) {
                const int cid = t * 256 + tid;
                const int row = cid >> 4, g = cid & 15;
                pa[t] = *reinterpret_cast<const bf16x8*>(&A [(m0 + row) * 512 + kb + g * 8]);
                pb[t] = *reinterpret_cast<const bf16x8*>(&BT[(n0 + row) * 512 + kb + g * 8]);
            }
        }
        const int ar = w * 16 + fm;
        #pragma unroll
        for (int ksub = 0; ksub < 4; ++ksub) {
            bf16x8 af = *reinterpret_cast<const bf16x8*>(&la[ar * 128 + (((ksub * 4 + fg) ^ (ar & 15)) * 8)]);
            #pragma unroll
            for (int c = 0; c < 4; ++c) {
                const int br = c * 16 + fm;
                bf16x8 bb = *reinterpret_cast<const bf16x8*>(&lb[br * 128 + (((ksub * 4 + fg) ^ (br & 15)) * 8)]);
                acc[c] = MFMA(af, bb, acc[c]);
            }
        }
    }
}

__global__ __launch_bounds__(256, 2) void k_gemm_qkv(
    const bf16* __restrict__ xb, const bf16* __restrict__ wqT,
    const bf16* __restrict__ wkT, const bf16* __restrict__ wvT,
    bf16* __restrict__ qo, bf16* __restrict__ ko, bf16* __restrict__ vTo)
{
    __shared__ bf16 la[64 * 128];
    __shared__ bf16 lb[64 * 128];
    const int m0 = blockIdx.x * 64, n0 = blockIdx.y * 64, z = blockIdx.z;
    const bf16* BT = (z == 0) ? wqT : (z == 1) ? wkT : wvT;
    f32x4 acc[4] = {};
    gemm_tile_64x64_bk128(xb, BT, m0, n0, la, lb, acc);
    const int w = threadIdx.x >> 6, lane = threadIdx.x & 63;
    const int fm = lane & 15, fg = lane >> 4;
    #pragma unroll
    for (int c = 0; c < 4; ++c)
        #pragma unroll
        for (int r = 0; r < 4; ++r) {
            const int m  = m0 + w * 16 + fg * 4 + r;
            const int nf = n0 + c * 16 + fm;
            const int b = m >> 11, tok = m & 2047;
            const int h = nf >> 6, d = nf & 63;
            const float v = acc[c][r];
            if (z == 0)      qo[((b * 8 + h) * 2048 + tok) * 64 + d] = (bf16)(v * 0.125f);
            else if (z == 1) ko[((b * 8 + h) * 2048 + tok) * 64 + d] = (bf16)v;
            else             vTo[((b * 8 + h) * 64 + d) * 2048 + tok] = (bf16)v;
        }
}

__global__ __launch_bounds__(256, 2) void k_gemm_out(
    const bf16* __restrict__ ao, const bf16* __restrict__ woT, float* __restrict__ out)
{
    __shared__ bf16 la[64 * 128];
    __shared__ bf16 lb[64 * 128];
    const int m0 = blockIdx.x * 64, n0 = blockIdx.y * 64;
    f32x4 acc[4] = {};
    gemm_tile_64x64_bk128(ao, woT, m0, n0, la, lb, acc);
    const int w = threadIdx.x >> 6, lane = threadIdx.x & 63;
    const int fm = lane & 15, fg = lane >> 4;
    #pragma unroll
    for (int c = 0; c < 4; ++c)
        #pragma unroll
        for (int r = 0; r < 4; ++r) {
            const int m  = m0 + w * 16 + fg * 4 + r;
            const int nf = n0 + c * 16 + fm;
            out[m * 512 + nf] = acc[c][r];
        }
}

// ---------------- barrier-free per-wave causal flash attention with relative bias ----------------
// grid (2048): one 64-thread block = one independent wave-task = 16 Q-rows x causal K-sweep.
// bh = blockIdx.x & 15 pins each head to XCD (bh&7) for K/V L2 residency.
// K/V/Er B-fragments are read directly from global (L2-resident); LDS only holds the
// wave-private G band and P tile (same-wave lgkmcnt ordering, NO __syncthreads anywhere).
__global__ __launch_bounds__(64, 4) void k_attn(
    const bf16* __restrict__ qg, const bf16* __restrict__ kg,
    const bf16* __restrict__ vg, const bf16* __restrict__ erB,
    bf16* __restrict__ ao)
{
    __shared__ bf16 gt[80 * 20];   // G band [t_local][q_row], stride 20 (pad)
    __shared__ bf16 lp[16 * 68];   // P [m][jl], stride 68 (pad)

    const int bh = blockIdx.x & 15;
    const int sr = blockIdx.x >> 4;                 // 0..127
    const int s  = (bh & 8) ? sr : (127 - sr);      // parity pairing balances triangle
    const int iw0 = s * 16;                         // this wave's first Q row
    const bf16* qp = qg + bh * 2048 * 64;
    const bf16* kp = kg + bh * 2048 * 64;
    const bf16* vp = vg + bh * 64 * 2048;

    const int lane = threadIdx.x;                   // 0..63
    const int fm = lane & 15, fg = lane >> 4;

    const bf16x8 aq0 = *reinterpret_cast<const bf16x8*>(&qp[(iw0 + fm) * 64 + fg * 8]);
    const bf16x8 aq1 = *reinterpret_cast<const bf16x8*>(&qp[(iw0 + fm) * 64 + 32 + fg * 8]);

    f32x4 oacc[4] = {};
    float mrow[4] = { -1e30f, -1e30f, -1e30f, -1e30f };
    float lrow[4] = { 0.f, 0.f, 0.f, 0.f };

    const int ntiles = (s >> 2) + 1;                // covers j <= iw0+15

    for (int jt = 0; jt < ntiles; ++jt) {
        const int j0 = jt * 64;

        // S = Q K^T (16x64), K fragments straight from global/L2
        f32x4 sa[4];
        #pragma unroll
        for (int cc = 0; cc < 4; ++cc) {
            const int br = j0 + cc * 16 + fm;
            bf16x8 b0 = *reinterpret_cast<const bf16x8*>(&kp[br * 64 + fg * 8]);
            bf16x8 b1 = *reinterpret_cast<const bf16x8*>(&kp[br * 64 + 32 + fg * 8]);
            f32x4 sv = {};
            sv = MFMA(aq0, b0, sv);
            sv = MFMA(aq1, b1, sv);
            sa[cc] = sv;
        }

        // G band: t_local in [0,79); er row = m0e + tr; rows >=2048 are zero-padded (masked positions only)
        const bf16* erp = erB + (2032 - iw0 + j0) * 64;
        #pragma unroll
        for (int u = 0; u < 5; ++u) {
            const int tr = u * 16 + fm;
            bf16x8 e0 = *reinterpret_cast<const bf16x8*>(&erp[tr * 64 + fg * 8]);
            bf16x8 e1 = *reinterpret_cast<const bf16x8*>(&erp[tr * 64 + 32 + fg * 8]);
            f32x4 g = {};
            g = MFMA(aq0, e0, g);
            g = MFMA(aq1, e1, g);
            bf16x4 gb = { (bf16)g[0], (bf16)g[1], (bf16)g[2], (bf16)g[3] };
            *reinterpret_cast<bf16x4*>(&gt[tr * 20 + fg * 4]) = gb;
        }

        // rel gather + causal mask + tile row-max  (t_local = 15 - m + jl)
        const int dmaxw = iw0 - j0;
        float mtile[4] = { -3e38f, -3e38f, -3e38f, -3e38f };
        #pragma unroll
        for (int cc = 0; cc < 4; ++cc)
            #pragma unroll
            for (int r = 0; r < 4; ++r) {
                const int m = fg * 4 + r;
                const int jl = cc * 16 + fm;
                float sv = sa[cc][r] + (float)gt[(15 - m + jl) * 20 + m];
                if (jl - m > dmaxw) sv = -3e38f;
                sa[cc][r] = sv;
                mtile[r] = fmaxf(mtile[r], sv);
            }
        float fac[4];
        #pragma unroll
        for (int r = 0; r < 4; ++r) {
            float v = mtile[r];
            v = fmaxf(v, __shfl_xor(v, 1, 64));
            v = fmaxf(v, __shfl_xor(v, 2, 64));
            v = fmaxf(v, __shfl_xor(v, 4, 64));
            v = fmaxf(v, __shfl_xor(v, 8, 64));
            const float mn = fmaxf(mrow[r], v);
            fac[r] = __expf(mrow[r] - mn);
            mrow[r] = mn;
        }
        float rs[4] = { 0.f, 0.f, 0.f, 0.f };
        #pragma unroll
        for (int cc = 0; cc < 4; ++cc)
            #pragma unroll
            for (int r = 0; r < 4; ++r) {
                const float p = __expf(sa[cc][r] - mrow[r]);
                rs[r] += p;
                lp[(fg * 4 + r) * 68 + cc * 16 + fm] = (bf16)p;
            }
        #pragma unroll
        for (int r = 0; r < 4; ++r) {
            float v = rs[r];
            v += __shfl_xor(v, 1, 64);
            v += __shfl_xor(v, 2, 64);
            v += __shfl_xor(v, 4, 64);
            v += __shfl_xor(v, 8, 64);
            lrow[r] = lrow[r] * fac[r] + v;
        }
        #pragma unroll
        for (int df = 0; df < 4; ++df)
            #pragma unroll
            for (int r = 0; r < 4; ++r)
                oacc[df][r] *= fac[r];

        // O += P V : P A-frags from wave-private LDS, V^T B-frags from global/L2
        bf16x8 ap0 = *reinterpret_cast<const bf16x8*>(&lp[fm * 68 + fg * 8]);
        bf16x8 ap1 = *reinterpret_cast<const bf16x8*>(&lp[fm * 68 + 32 + fg * 8]);
        #pragma unroll
        for (int df = 0; df < 4; ++df) {
            const int dr = df * 16 + fm;
            bf16x8 b0 = *reinterpret_cast<const bf16x8*>(&vp[dr * 2048 + j0 + fg * 8]);
            bf16x8 b1 = *reinterpret_cast<const bf16x8*>(&vp[dr * 2048 + j0 + 32 + fg * 8]);
            oacc[df] = MFMA(ap0, b0, oacc[df]);
            oacc[df] = MFMA(ap1, b1, oacc[df]);
        }
    }

    // epilogue: ao[b][i][h*64+d]
    const int b = bh >> 3, h = bh & 7;
    #pragma unroll
    for (int df = 0; df < 4; ++df)
        #pragma unroll
        for (int r = 0; r < 4; ++r) {
            const int i = iw0 + fg * 4 + r;
            const int d = df * 16 + fm;
            ao[(b * 2048 + i) * 512 + h * 64 + d] = (bf16)(oacc[df][r] / lrow[r]);
        }
}

// ---------------- host launcher ----------------

extern "C" void kernel_launch(void* const* d_in, const int* in_sizes, int n_in,
                              void* d_out, int out_size, void* d_ws, size_t ws_size,
                              hipStream_t stream) {
    (void)in_sizes; (void)n_in; (void)out_size; (void)ws_size;
    const float* x  = (const float*)d_in[0];
    const float* Wq = (const float*)d_in[1];
    const float* Wk = (const float*)d_in[2];
    const float* Wv = (const float*)d_in[3];
    const float* Wo = (const float*)d_in[4];
    const float* Er = (const float*)d_in[5];
    float* out = (float*)d_out;

    char* ws = (char*)d_ws;
    bf16* xb  = (bf16*)(ws);                  // 4096*512        = 4,194,304 B
    bf16* wqT = (bf16*)(ws + 4194304);
    bf16* wkT = (bf16*)(ws + 4718592);
    bf16* wvT = (bf16*)(ws + 5242880);
    bf16* woT = (bf16*)(ws + 5767168);
    bf16* erB = (bf16*)(ws + 6291456);        // 2176*64*2
    bf16* q   = (bf16*)(ws + 6569984);
    bf16* k   = (bf16*)(ws + 10764288);
    bf16* vT  = (bf16*)(ws + 14958592);
    bf16* ao  = (bf16*)(ws + 19152896);       // end 23,347,200 B

    k_cast_x<<<dim3(2048), dim3(256), 0, stream>>>(x, xb);
    k_prep_w<<<dim3(8, 8, 4), dim3(256), 0, stream>>>(Wq, Wk, Wv, Wo, wqT, wkT, wvT, woT);
    k_prep_er<<<dim3(544), dim3(256), 0, stream>>>(Er, erB);
    k_gemm_qkv<<<dim3(64, 8, 3), dim3(256), 0, stream>>>(xb, wqT, wkT, wvT, q, k, vT);
    k_attn<<<dim3(2048), dim3(64), 0, stream>>>(q, k, vT, erB, ao);
    k_gemm_out<<<dim3(64, 8), dim3(256), 0, stream>>>(ao, woT, out);
}

// Round 11
// 227.207 us; speedup vs baseline: 1.1645x; 1.1645x over previous
//
#include <hip/hip_runtime.h>
#include <stdint.h>

typedef __bf16 bf16;
typedef __bf16 bf16x4 __attribute__((ext_vector_type(4)));
typedef __bf16 bf16x8 __attribute__((ext_vector_type(8)));
typedef float f32x4 __attribute__((ext_vector_type(4)));

#define MFMA(a, b, c) __builtin_amdgcn_mfma_f32_16x16x32_bf16(a, b, c, 0, 0, 0)

// ---------------- prep kernels ----------------

__global__ void k_cast_x(const float* __restrict__ x, bf16* __restrict__ xb) {
    int i = (blockIdx.x * 256 + threadIdx.x) * 4;
    float4 v = *reinterpret_cast<const float4*>(x + i);
    bf16x4 o = { (bf16)v.x, (bf16)v.y, (bf16)v.z, (bf16)v.w };
    *reinterpret_cast<bf16x4*>(xb + i) = o;
}

__global__ void k_prep_w(const float* __restrict__ w0, const float* __restrict__ w1,
                         const float* __restrict__ w2, const float* __restrict__ w3,
                         bf16* __restrict__ o0, bf16* __restrict__ o1,
                         bf16* __restrict__ o2, bf16* __restrict__ o3) {
    __shared__ float t[64][65];
    const float* w; bf16* o;
    if (blockIdx.z == 0)      { w = w0; o = o0; }
    else if (blockIdx.z == 1) { w = w1; o = o1; }
    else if (blockIdx.z == 2) { w = w2; o = o2; }
    else                      { w = w3; o = o3; }
    int n0 = blockIdx.x * 64, k0 = blockIdx.y * 64;
    int tx = threadIdx.x & 63, ty = threadIdx.x >> 6;
    #pragma unroll
    for (int s = 0; s < 16; ++s) {
        int r = ty * 16 + s;
        t[r][tx] = w[(k0 + r) * 512 + n0 + tx];
    }
    __syncthreads();
    #pragma unroll
    for (int s = 0; s < 16; ++s) {
        int r = ty * 16 + s;
        o[(n0 + r) * 512 + k0 + tx] = (bf16)t[tx][r];
    }
}

__global__ void k_prep_er(const float* __restrict__ er, bf16* __restrict__ erB) {
    int i = blockIdx.x * 256 + threadIdx.x;
    int r = i >> 6;
    erB[i] = (r < 2048) ? (bf16)er[i] : (bf16)0.0f;
}

// ---------------- 64x64 GEMM tile core (unchanged from round 7 for comparability) ----------------

__device__ __forceinline__ void gemm_tile_64x64(
    const bf16* __restrict__ A, const bf16* __restrict__ BT,
    int m0, int n0, bf16* la, bf16* lb, f32x4 (&acc)[4])
{
    const int tid = threadIdx.x;
    const int w = tid >> 6, lane = tid & 63;
    const int fm = lane & 15, fg = lane >> 4;
    const int srow = tid >> 2, sch = tid & 3;
    const int sph = sch ^ ((srow >> 1) & 3);
    for (int kt = 0; kt < 16; ++kt) {
        const int kb = kt * 32;
        __syncthreads();
        *reinterpret_cast<bf16x8*>(&la[srow * 32 + sph * 8]) =
            *reinterpret_cast<const bf16x8*>(&A[(m0 + srow) * 512 + kb + sch * 8]);
        *reinterpret_cast<bf16x8*>(&lb[srow * 32 + sph * 8]) =
            *reinterpret_cast<const bf16x8*>(&BT[(n0 + srow) * 512 + kb + sch * 8]);
        __syncthreads();
        const int ar = w * 16 + fm;
        bf16x8 af = *reinterpret_cast<const bf16x8*>(&la[ar * 32 + (fg ^ ((ar >> 1) & 3)) * 8]);
        #pragma unroll
        for (int c = 0; c < 4; ++c) {
            const int br = c * 16 + fm;
            bf16x8 bb = *reinterpret_cast<const bf16x8*>(&lb[br * 32 + (fg ^ ((br >> 1) & 3)) * 8]);
            acc[c] = MFMA(af, bb, acc[c]);
        }
    }
}

__global__ __launch_bounds__(256, 2) void k_gemm_qkv(
    const bf16* __restrict__ xb, const bf16* __restrict__ wqT,
    const bf16* __restrict__ wkT, const bf16* __restrict__ wvT,
    bf16* __restrict__ qo, bf16* __restrict__ ko, bf16* __restrict__ vTo)
{
    __shared__ bf16 la[64 * 32];
    __shared__ bf16 lb[64 * 32];
    const int m0 = blockIdx.x * 64, n0 = blockIdx.y * 64, z = blockIdx.z;
    const bf16* BT = (z == 0) ? wqT : (z == 1) ? wkT : wvT;
    f32x4 acc[4] = {};
    gemm_tile_64x64(xb, BT, m0, n0, la, lb, acc);
    const int w = threadIdx.x >> 6, lane = threadIdx.x & 63;
    const int fm = lane & 15, fg = lane >> 4;
    #pragma unroll
    for (int c = 0; c < 4; ++c)
        #pragma unroll
        for (int r = 0; r < 4; ++r) {
            const int m  = m0 + w * 16 + fg * 4 + r;
            const int nf = n0 + c * 16 + fm;
            const int b = m >> 11, tok = m & 2047;
            const int h = nf >> 6, d = nf & 63;
            const float v = acc[c][r];
            if (z == 0)      qo[((b * 8 + h) * 2048 + tok) * 64 + d] = (bf16)(v * 0.125f);
            else if (z == 1) ko[((b * 8 + h) * 2048 + tok) * 64 + d] = (bf16)v;
            else             vTo[((b * 8 + h) * 64 + d) * 2048 + tok] = (bf16)v;
        }
}

__global__ __launch_bounds__(256, 2) void k_gemm_out(
    const bf16* __restrict__ ao, const bf16* __restrict__ woT, float* __restrict__ out)
{
    __shared__ bf16 la[64 * 32];
    __shared__ bf16 lb[64 * 32];
    const int m0 = blockIdx.x * 64, n0 = blockIdx.y * 64;
    f32x4 acc[4] = {};
    gemm_tile_64x64(ao, woT, m0, n0, la, lb, acc);
    const int w = threadIdx.x >> 6, lane = threadIdx.x & 63;
    const int fm = lane & 15, fg = lane >> 4;
    #pragma unroll
    for (int c = 0; c < 4; ++c)
        #pragma unroll
        for (int r = 0; r < 4; ++r) {
            const int m  = m0 + w * 16 + fg * 4 + r;
            const int nf = n0 + c * 16 + fm;
            out[m * 512 + nf] = acc[c][r];
        }
}

// ---------------- causal flash attention, KVBLK=64, G-path software-pipelined ----------------
// grid (32, 16), 256 threads / 4 waves; wave w owns Q rows [16w,16w+16).
// G band for tile n+1 is computed during tile n (wave-private double-buffered gt),
// so iteration n's gather reads a long-finished buffer: G off the critical path.
__global__ __launch_bounds__(256, 2) void k_attn(
    const bf16* __restrict__ qg, const bf16* __restrict__ kg,
    const bf16* __restrict__ vg, const bf16* __restrict__ erB,
    bf16* __restrict__ ao)
{
    __shared__ bf16 lk[64 * 64];         // K tile [j][d], XOR-swizzled chunks
    __shared__ bf16 lv[64 * 64];         // V^T tile [d][j], swizzled
    __shared__ bf16 gt[2][4 * 128 * 20]; // double-buffered per-wave G band [t][cw], stride 20
    __shared__ bf16 lp[64 * 64];         // P, swizzled

    const int qt = 31 - blockIdx.x;      // heavy tiles first
    const int bh = blockIdx.y;
    const int i0 = qt * 64;
    const bf16* qp = qg + bh * 2048 * 64;
    const bf16* kp = kg + bh * 2048 * 64;
    const bf16* vp = vg + bh * 64 * 2048;

    const int tid = threadIdx.x;
    const int w = tid >> 6, lane = tid & 63;
    const int fm = lane & 15, fg = lane >> 4;

    const bf16x8 aq0 = *reinterpret_cast<const bf16x8*>(&qp[(i0 + w * 16 + fm) * 64 + fg * 8]);
    const bf16x8 aq1 = *reinterpret_cast<const bf16x8*>(&qp[(i0 + w * 16 + fm) * 64 + 32 + fg * 8]);

    const int srow = tid >> 3, sg = tid & 7, sph = sg ^ (srow & 7);

    // prefetch first K/V tile into registers
    bf16x8 pk[2], pv[2];
    #pragma unroll
    for (int t = 0; t < 2; ++t) {
        const int row = srow + t * 32;
        pk[t] = *reinterpret_cast<const bf16x8*>(&kp[row * 64 + sg * 8]);
        pv[t] = *reinterpret_cast<const bf16x8*>(&vp[row * 2048 + sg * 8]);
    }

    // prologue: G band for tile 0 into gt[0]
    int buf = 0;
    {
        const bf16* erp = erB + (1984 - i0) * 64;
        bf16* gtb = &gt[0][w * 2560];
        #pragma unroll
        for (int u = 0; u < 8; ++u) {
            const int tr = u * 16 + fm;
            bf16x8 e0 = *reinterpret_cast<const bf16x8*>(&erp[tr * 64 + fg * 8]);
            bf16x8 e1 = *reinterpret_cast<const bf16x8*>(&erp[tr * 64 + 32 + fg * 8]);
            f32x4 g = {};
            g = MFMA(aq0, e0, g);
            g = MFMA(aq1, e1, g);
            bf16x4 gb = { (bf16)g[0], (bf16)g[1], (bf16)g[2], (bf16)g[3] };
            *reinterpret_cast<bf16x4*>(&gtb[tr * 20 + fg * 4]) = gb;
        }
    }

    f32x4 oacc[4] = {};
    float mrow[4] = { -1e30f, -1e30f, -1e30f, -1e30f };
    float lrow[4] = { 0.f, 0.f, 0.f, 0.f };

    for (int j0 = 0; j0 <= i0; j0 += 64) {
        __syncthreads();                       // prev iteration's lk/lv/lp readers done
        #pragma unroll
        for (int t = 0; t < 2; ++t) {
            const int row = srow + t * 32;
            *reinterpret_cast<bf16x8*>(&lk[row * 64 + sph * 8]) = pk[t];
            *reinterpret_cast<bf16x8*>(&lv[row * 64 + sph * 8]) = pv[t];
        }
        __syncthreads();
        const bool more = (j0 + 64 <= i0);
        if (more) {                            // prefetch next K/V under compute
            const int j0n = j0 + 64;
            #pragma unroll
            for (int t = 0; t < 2; ++t) {
                const int row = srow + t * 32;
                pk[t] = *reinterpret_cast<const bf16x8*>(&kp[(j0n + row) * 64 + sg * 8]);
                pv[t] = *reinterpret_cast<const bf16x8*>(&vp[row * 2048 + j0n + sg * 8]);
            }
        }

        // S = Q K^T  (wave strip 16x64)
        f32x4 sa[4];
        #pragma unroll
        for (int cc = 0; cc < 4; ++cc) {
            const int br = cc * 16 + fm;
            bf16x8 b0 = *reinterpret_cast<const bf16x8*>(&lk[br * 64 + ((fg     ^ (br & 7)) * 8)]);
            bf16x8 b1 = *reinterpret_cast<const bf16x8*>(&lk[br * 64 + (((4+fg) ^ (br & 7)) * 8)]);
            f32x4 sv = {};
            sv = MFMA(aq0, b0, sv);
            sv = MFMA(aq1, b1, sv);
            sa[cc] = sv;
        }

        // G band for NEXT tile -> other buffer (wave-private; consumed next iteration)
        if (more) {
            const bf16* erp = erB + (1984 - i0 + j0 + 64) * 64;
            bf16* gtb = &gt[buf ^ 1][w * 2560];
            #pragma unroll
            for (int u = 0; u < 8; ++u) {
                const int tr = u * 16 + fm;
                bf16x8 e0 = *reinterpret_cast<const bf16x8*>(&erp[tr * 64 + fg * 8]);
                bf16x8 e1 = *reinterpret_cast<const bf16x8*>(&erp[tr * 64 + 32 + fg * 8]);
                f32x4 g = {};
                g = MFMA(aq0, e0, g);
                g = MFMA(aq1, e1, g);
                bf16x4 gb = { (bf16)g[0], (bf16)g[1], (bf16)g[2], (bf16)g[3] };
                *reinterpret_cast<bf16x4*>(&gtb[tr * 20 + fg * 4]) = gb;
            }
        }

        // rel gather (from gt[buf], computed last iteration) + causal mask + row-max
        const bf16* gtr = &gt[buf][w * 2560];
        const int dmax = i0 - j0;
        float mtile[4] = { -3e38f, -3e38f, -3e38f, -3e38f };
        #pragma unroll
        for (int cc = 0; cc < 4; ++cc)
            #pragma unroll
            for (int r = 0; r < 4; ++r) {
                const int cw = fg * 4 + r;
                const int il = w * 16 + cw;
                const int jl = cc * 16 + fm;
                float sv = sa[cc][r] + (float)gtr[(63 - il + jl) * 20 + cw];
                if (jl - il > dmax) sv = -3e38f;
                sa[cc][r] = sv;
                mtile[r] = fmaxf(mtile[r], sv);
            }
        float fac[4];
        #pragma unroll
        for (int r = 0; r < 4; ++r) {
            float v = mtile[r];
            v = fmaxf(v, __shfl_xor(v, 1, 64));
            v = fmaxf(v, __shfl_xor(v, 2, 64));
            v = fmaxf(v, __shfl_xor(v, 4, 64));
            v = fmaxf(v, __shfl_xor(v, 8, 64));
            const float mn = fmaxf(mrow[r], v);
            fac[r] = __expf(mrow[r] - mn);
            mrow[r] = mn;
        }
        float rs[4] = { 0.f, 0.f, 0.f, 0.f };
        #pragma unroll
        for (int cc = 0; cc < 4; ++cc)
            #pragma unroll
            for (int r = 0; r < 4; ++r) {
                const float p = __expf(sa[cc][r] - mrow[r]);
                rs[r] += p;
                const int il = w * 16 + fg * 4 + r;
                const int jl = cc * 16 + fm;
                lp[il * 64 + ((((jl >> 3) ^ (il & 7)) << 3) | (jl & 7))] = (bf16)p;
            }
        #pragma unroll
        for (int r = 0; r < 4; ++r) {
            float v = rs[r];
            v += __shfl_xor(v, 1, 64);
            v += __shfl_xor(v, 2, 64);
            v += __shfl_xor(v, 4, 64);
            v += __shfl_xor(v, 8, 64);
            lrow[r] = lrow[r] * fac[r] + v;
        }
        #pragma unroll
        for (int df = 0; df < 4; ++df)
            #pragma unroll
            for (int r = 0; r < 4; ++r)
                oacc[df][r] *= fac[r];
        // O += P V  (P from LDS, same-wave rows)
        const int ar = w * 16 + fm;
        bf16x8 ap0 = *reinterpret_cast<const bf16x8*>(&lp[ar * 64 + ((fg     ^ (ar & 7)) * 8)]);
        bf16x8 ap1 = *reinterpret_cast<const bf16x8*>(&lp[ar * 64 + (((4+fg) ^ (ar & 7)) * 8)]);
        #pragma unroll
        for (int df = 0; df < 4; ++df) {
            const int dr = df * 16 + fm;
            bf16x8 b0 = *reinterpret_cast<const bf16x8*>(&lv[dr * 64 + ((fg     ^ (dr & 7)) * 8)]);
            bf16x8 b1 = *reinterpret_cast<const bf16x8*>(&lv[dr * 64 + (((4+fg) ^ (dr & 7)) * 8)]);
            oacc[df] = MFMA(ap0, b0, oacc[df]);
            oacc[df] = MFMA(ap1, b1, oacc[df]);
        }
        buf ^= 1;
    }

    // epilogue: ao[b][i][h*64+d]
    const int b = bh >> 3, h = bh & 7;
    #pragma unroll
    for (int df = 0; df < 4; ++df)
        #pragma unroll
        for (int r = 0; r < 4; ++r) {
            const int i = i0 + w * 16 + fg * 4 + r;
            const int d = df * 16 + fm;
            ao[(b * 2048 + i) * 512 + h * 64 + d] = (bf16)(oacc[df][r] / lrow[r]);
        }
}

// ---------------- host launcher ----------------

extern "C" void kernel_launch(void* const* d_in, const int* in_sizes, int n_in,
                              void* d_out, int out_size, void* d_ws, size_t ws_size,
                              hipStream_t stream) {
    (void)in_sizes; (void)n_in; (void)out_size; (void)ws_size;
    const float* x  = (const float*)d_in[0];
    const float* Wq = (const float*)d_in[1];
    const float* Wk = (const float*)d_in[2];
    const float* Wv = (const float*)d_in[3];
    const float* Wo = (const float*)d_in[4];
    const float* Er = (const float*)d_in[5];
    float* out = (float*)d_out;

    char* ws = (char*)d_ws;
    bf16* xb  = (bf16*)(ws);                  // 4096*512        = 4,194,304 B
    bf16* wqT = (bf16*)(ws + 4194304);
    bf16* wkT = (bf16*)(ws + 4718592);
    bf16* wvT = (bf16*)(ws + 5242880);
    bf16* woT = (bf16*)(ws + 5767168);
    bf16* erB = (bf16*)(ws + 6291456);        // 2176*64*2
    bf16* q   = (bf16*)(ws + 6569984);
    bf16* k   = (bf16*)(ws + 10764288);
    bf16* vT  = (bf16*)(ws + 14958592);
    bf16* ao  = (bf16*)(ws + 19152896);       // end 23,347,200 B

    k_cast_x<<<dim3(2048), dim3(256), 0, stream>>>(x, xb);
    k_prep_w<<<dim3(8, 8, 4), dim3(256), 0, stream>>>(Wq, Wk, Wv, Wo, wqT, wkT, wvT, woT);
    k_prep_er<<<dim3(544), dim3(256), 0, stream>>>(Er, erB);
    k_gemm_qkv<<<dim3(64, 8, 3), dim3(256), 0, stream>>>(xb, wqT, wkT, wvT, q, k, vT);
    k_attn<<<dim3(32, 16), dim3(256), 0, stream>>>(q, k, vT, erB, ao);
    k_gemm_out<<<dim3(64, 8), dim3(256), 0, stream>>>(ao, woT, out);
}